// Round 6
// baseline (585.437 us; speedup 1.0000x reference)
//
#include <hip/hip_runtime.h>

// ---------------- problem constants ----------------
#define N_TOK 8192      // B*S tokens
#define H_DIM 1024
#define I_DIM 2048
#define N_EXP 8
#define TOPK  2
#define CAP   18432     // 16384 + 8*256 (per-expert padding to 256)
#define MT_MAX 72       // CAP / 256

// ---------------- workspace layout (bytes) ----------------
#define OFF_TOPK_I 0u          // 16384 i32
#define OFF_TOPK_W 65536u      // 16384 f32 (RAW softmax probs of chosen experts)
#define OFF_COUNTS 131072u     // 8 i32
#define OFF_LOAD   131104u     // 8 f32
#define OFF_CURSOR 131136u     // 8 i32
#define OFF_PO     131168u     // 16 i32
#define OFF_TILE_E 131232u     // 128 i32 (72 used)
#define OFF_BTOK   131744u     // 18432 i32
#define OFF_BW     205472u     // 18432 f32
#define CTRL_BYTES 279200u     // memset covers everything above
#define OFF_TSLOT  279552u     // 16384 i32 — fully overwritten by k_bucket, no memset
#define OFF_WGT  1048576u                      // 8*2048*1024*2 = 33554432
#define OFF_WUT  (OFF_WGT + 33554432u)
#define OFF_WDT  (OFF_WUT + 33554432u)
#define OFF_HB   (OFF_WDT + 33554432u)         // 18432*2048*2 = 75497472
#define OFF_XB   (OFF_HB + 75497472u)          // 8192*1024*2 = 16777216 (x in bf16)
// obuf (18432*1024 bf16 = 37.7 MB) reuses WGT+WUT (dead after gemm1)

typedef __attribute__((ext_vector_type(8))) short bf16x8;
typedef __attribute__((ext_vector_type(8))) unsigned short u16x8;
typedef __attribute__((ext_vector_type(4))) unsigned short u16x4;
typedef __attribute__((ext_vector_type(4))) float f32x4;
typedef __attribute__((ext_vector_type(16))) float f32x16;

#define BAR() __builtin_amdgcn_s_barrier()
#define PRIO1() __builtin_amdgcn_s_setprio(1)
#define PRIO0() __builtin_amdgcn_s_setprio(0)
#define WAITV0() asm volatile("s_waitcnt vmcnt(0)" ::: "memory")
#define WAITV6() asm volatile("s_waitcnt vmcnt(6)" ::: "memory")

__device__ __forceinline__ unsigned short f2bf(float f) {
  union { float f; unsigned int u; } v; v.f = f;
  unsigned int r = (v.u + 0x7FFFu + ((v.u >> 16) & 1u)) >> 16;
  return (unsigned short)r;
}
__device__ __forceinline__ float bf2f(unsigned short u) {
  union { unsigned int u; float f; } v; v.u = ((unsigned int)u) << 16;
  return v.f;
}
__device__ __forceinline__ u16x8 pack8(float4 a, float4 b) {
  u16x8 r;
  r[0] = f2bf(a.x); r[1] = f2bf(a.y); r[2] = f2bf(a.z); r[3] = f2bf(a.w);
  r[4] = f2bf(b.x); r[5] = f2bf(b.y); r[6] = f2bf(b.z); r[7] = f2bf(b.w);
  return r;
}
__device__ __forceinline__ f32x16 mfma3216(bf16x8 a, bf16x8 b, f32x16 c) {
  return __builtin_amdgcn_mfma_f32_32x32x16_bf16(a, b, c, 0, 0, 0);
}
// async global->LDS, 16B per lane; lds dest must be wave-uniform base (HW adds lane*16)
__device__ __forceinline__ void gll16(const void* g, void* l) {
  __builtin_amdgcn_global_load_lds(
      (const __attribute__((address_space(1))) unsigned int*)g,
      (__attribute__((address_space(3))) unsigned int*)l, 16, 0, 0);
}

// ---------------- K_prep: fused {router + x->bf16 cast} ∥ {weight transpose} ----------------
// blocks 0..2047: router (latency-bound). blocks 2048..14335: transpose (BW-bound).
// Co-residency overlaps the two regimes.
__global__ __launch_bounds__(256) void k_prep(
    const float* __restrict__ x, const float* __restrict__ gw,
    const float* __restrict__ wg, const float* __restrict__ wu, const float* __restrict__ wd,
    unsigned short* __restrict__ xb,
    unsigned short* __restrict__ wgT, unsigned short* __restrict__ wuT,
    unsigned short* __restrict__ wdT,
    int* __restrict__ topk_i, float* __restrict__ topk_w)
{
  __shared__ unsigned short lds[64][65];
  if (blockIdx.x < 2048) {
    // ---- router: 1 wave per token, float4 loads, fused cast ----
    int wave = threadIdx.x >> 6, lane = threadIdx.x & 63;
    int t = blockIdx.x * 4 + wave;
    const float4* xr4 = (const float4*)(x + (size_t)t * H_DIM);
    float acc[8];
#pragma unroll
    for (int e = 0; e < 8; ++e) acc[e] = 0.f;
#pragma unroll
    for (int it = 0; it < 4; ++it) {
      int hq = it * 64 + lane;            // h = hq*4
      float4 xv = xr4[hq];
      u16x4 xo; xo[0] = f2bf(xv.x); xo[1] = f2bf(xv.y); xo[2] = f2bf(xv.z); xo[3] = f2bf(xv.w);
      *(u16x4*)&xb[(size_t)t * H_DIM + hq * 4] = xo;   // 8B/lane coalesced
      float xs[4] = {xv.x, xv.y, xv.z, xv.w};
#pragma unroll
      for (int j = 0; j < 4; ++j) {
        float4 g0 = *(const float4*)&gw[(hq * 4 + j) * 8];
        float4 g1 = *(const float4*)&gw[(hq * 4 + j) * 8 + 4];
        acc[0] += xs[j] * g0.x; acc[1] += xs[j] * g0.y; acc[2] += xs[j] * g0.z; acc[3] += xs[j] * g0.w;
        acc[4] += xs[j] * g1.x; acc[5] += xs[j] * g1.y; acc[6] += xs[j] * g1.z; acc[7] += xs[j] * g1.w;
      }
    }
#pragma unroll
    for (int off = 32; off > 0; off >>= 1) {
#pragma unroll
      for (int e = 0; e < 8; ++e) acc[e] += __shfl_xor(acc[e], off);
    }
    if (lane == 0) {
      float m = acc[0];
#pragma unroll
      for (int e = 1; e < 8; ++e) m = fmaxf(m, acc[e]);
      float p[8], s = 0.f;
#pragma unroll
      for (int e = 0; e < 8; ++e) { p[e] = __expf(acc[e] - m); s += p[e]; }
      float inv = 1.f / s;
#pragma unroll
      for (int e = 0; e < 8; ++e) p[e] *= inv;
      int i1 = 0;
#pragma unroll
      for (int e = 1; e < 8; ++e) if (p[e] > p[i1]) i1 = e;   // strict > = lowest-index ties
      int i2 = (i1 == 0) ? 1 : 0;
#pragma unroll
      for (int e = 0; e < 8; ++e) if (e != i1 && p[e] > p[i2]) i2 = e;
      topk_i[t * 2]     = i1; topk_i[t * 2 + 1] = i2;
      topk_w[t * 2]     = p[i1]; topk_w[t * 2 + 1] = p[i2];   // RAW probs
    }
    return;
  }
  // ---- transpose: f32 -> bf16, 3 weight tensors ----
  int bid = blockIdx.x - 2048;
  int m = bid / 4096; int rem = bid % 4096;
  const float* src; unsigned short* dst; int R, C;
  if (m == 0)      { src = wg; dst = wgT; R = 1024; C = 2048; }
  else if (m == 1) { src = wu; dst = wuT; R = 1024; C = 2048; }
  else             { src = wd; dst = wdT; R = 2048; C = 1024; }
  int e = rem / 512; int trem = rem % 512;
  int tcc = C / 64;
  int r0 = (trem / tcc) * 64, c0 = (trem % tcc) * 64;
  size_t ebase = (size_t)e * R * C;
  dst += ebase;
  int tid = threadIdx.x;
  int lr = tid >> 3;            // 0..31
  int lc = (tid & 7) * 8;       // 0..56
#pragma unroll
  for (int p = 0; p < 2; ++p) {
    int row = p * 32 + lr;
    size_t off = ebase + (size_t)(r0 + row) * C + c0 + lc;
    float4 q0 = *(const float4*)&src[off];
    float4 q1 = *(const float4*)&src[off + 4];
    unsigned short tmp[8]; *(u16x8*)tmp = pack8(q0, q1);
#pragma unroll
    for (int j = 0; j < 8; ++j) lds[row][lc + j] = tmp[j];
  }
  __syncthreads();
#pragma unroll
  for (int p = 0; p < 2; ++p) {
    int drow = p * 32 + lr;     // local c index
    unsigned short tmp[8];
#pragma unroll
    for (int j = 0; j < 8; ++j) tmp[j] = lds[lc + j][drow];
    *(u16x8*)&dst[(size_t)(c0 + drow) * R + r0 + lc] = *(const u16x8*)tmp;
  }
}

// ---------------- K3b: histogram via LDS aggregation -> 128 global atomics total ----------------
__global__ __launch_bounds__(256) void k_hist(
    const int* __restrict__ topk_i, const float* __restrict__ topk_w,
    int* __restrict__ counts, float* __restrict__ loadw)
{
  __shared__ int c[8]; __shared__ float l[8];
  int tid = threadIdx.x;
  if (tid < 8) { c[tid] = 0; l[tid] = 0.f; }
  __syncthreads();
  int base = blockIdx.x * 1024 + tid * 4;
#pragma unroll
  for (int j = 0; j < 4; ++j) {
    int e = topk_i[base + j];
    float w = topk_w[base + j];
    atomicAdd(&c[e], 1);
    atomicAdd(&l[e], w);
  }
  __syncthreads();
  if (tid < 8) { atomicAdd(&counts[tid], c[tid]); atomicAdd(&loadw[tid], l[tid]); }
}

// ---------------- K4: padded offsets (256) + tile->expert map + aux loss ----------------
__global__ __launch_bounds__(256) void k_offsets(
    const int* __restrict__ counts, const float* __restrict__ loadw,
    int* __restrict__ po, int* __restrict__ tile_e, float* __restrict__ out)
{
  __shared__ int spo[9];
  if (threadIdx.x == 0) {
    int a = 0;
    for (int e = 0; e < 8; ++e) { spo[e] = a; po[e] = a; a += (counts[e] + 255) & ~255; }
    spo[8] = a; po[8] = a;
    float s = 0.f;
    for (int e = 0; e < 8; ++e) s += loadw[e] * (float)counts[e];
    out[(size_t)N_TOK * H_DIM] =
        s * ((float)N_EXP * 1e-3f) / ((float)N_TOK * (float)N_TOK * (float)TOPK);
  }
  __syncthreads();
  int mt = threadIdx.x;
  if (mt < MT_MAX) {
    int te = -1, beg = mt * 256;
    if (beg < spo[8]) {
      for (int e = 0; e < 8; ++e) if (beg >= spo[e] && beg < spo[e + 1]) te = e;
    }
    tile_e[mt] = te;
  }
}

// ---------------- K5: bucket fill ----------------
__global__ __launch_bounds__(256) void k_bucket(
    const int* __restrict__ topk_i, const float* __restrict__ topk_w,
    const int* __restrict__ po, int* __restrict__ cursor,
    int* __restrict__ btok, float* __restrict__ bw, int* __restrict__ tslot)
{
  __shared__ int c[8];
  __shared__ int basee[8];
  int tid = threadIdx.x;
  if (tid < 8) c[tid] = 0;
  __syncthreads();
  int base = blockIdx.x * 1024 + tid * 4;
  int e4[4], r4[4]; float w4[4];
#pragma unroll
  for (int j = 0; j < 4; ++j) {
    int idx = base + j;
    int e = topk_i[idx];
    e4[j] = e;
    r4[j] = atomicAdd(&c[e], 1);
    int t = idx >> 1;
    float p0 = topk_w[t * 2], p1 = topk_w[t * 2 + 1];
    w4[j] = topk_w[idx] / (p0 + p1);
  }
  __syncthreads();
  if (tid < 8) basee[tid] = po[tid] + atomicAdd(&cursor[tid], c[tid]);
  __syncthreads();
#pragma unroll
  for (int j = 0; j < 4; ++j) {
    int idx = base + j;
    int slot = basee[e4[j]] + r4[j];
    btok[slot] = idx >> 1;
    bw[slot] = w4[j];
    tslot[idx] = slot;
  }
}

// ---------------- K6: GEMM1 256x128, 32x32x16 MFMA, G/U wave-split, BK=64 ----------------
// grid: x = nt (16), y = mt (72); 512 threads = 8 waves: waves 0-3 G, 4-7 U.
// Wave tile 128x64 = 4mf x 2nf of 32x32. LDS 128KB: 2 x (A 32KB + Bg 16KB + Bu 16KB).
__global__ __launch_bounds__(512, 2) void k_gemm1(
    const unsigned short* __restrict__ xb,
    const unsigned short* __restrict__ wgT, const unsigned short* __restrict__ wuT,
    const int* __restrict__ btok, const int* __restrict__ tile_e,
    unsigned short* __restrict__ hbuf)
{
  int nt = blockIdx.x, mt = blockIdx.y;
  int e = tile_e[mt];
  if (e < 0) return;
  __shared__ unsigned char smem[131072];
  unsigned short* lds = (unsigned short*)smem;   // staging (main loop)
  float* uex = (float*)smem;                     // U-exchange (epilogue, aliases staging)
  int tid = threadIdx.x;
  int wave = tid >> 6, lane = tid & 63;
  int grp = wave >> 2;                 // 0 = G-waves, 1 = U-waves
  int g4 = wave & 3;
  int wm = g4 >> 1, wn = g4 & 1;       // 2M x 2N of 128x64 wave tiles
  int l32 = lane & 31, half = lane >> 5;

  // ---- staging geometry (512 threads; chunk = 16B; src chunk XOR row&7; dest linear) ----
  const unsigned short* srcA[4]; unsigned dstA[4];
#pragma unroll
  for (int c = 0; c < 4; ++c) {
    int idx = c * 512 + wave * 64 + lane;          // 0..2047 over A tile 16B-chunks
    int row = idx >> 3;                            // 0..255
    int ch  = (idx & 7) ^ (row & 7);               // swizzled source chunk
    int tok = btok[mt * 256 + row];                // pad slots 0 (memset) -> safe
    srcA[c] = xb + (size_t)tok * H_DIM + ch * 8;
    dstA[c] = (unsigned)(c * 512 + wave * 64) * 8; // linear LDS elems (lane adds 16B)
  }
  const unsigned short* srcG[2]; const unsigned short* srcU[2]; unsigned dstB[2];
#pragma unroll
  for (int c = 0; c < 2; ++c) {
    int idx = c * 512 + wave * 64 + lane;          // 0..1023 over B tile
    int col = idx >> 3;                            // 0..127 (B row = output col)
    int ch  = (idx & 7) ^ (col & 7);
    srcG[c] = wgT + ((size_t)e * I_DIM + nt * 128 + col) * H_DIM + ch * 8;
    srcU[c] = wuT + ((size_t)e * I_DIM + nt * 128 + col) * H_DIM + ch * 8;
    dstB[c] = (unsigned)(c * 512 + wave * 64) * 8;
  }
  unsigned breg = grp ? 24576u : 16384u;           // my B region (elems)

  // ---- precomputed swizzled read offsets (static-indexed; stay in VGPRs) ----
  unsigned aofs[4][4], bofs[2][4];
#pragma unroll
  for (int mf = 0; mf < 4; ++mf)
#pragma unroll
    for (int ks = 0; ks < 4; ++ks)
      aofs[mf][ks] = (unsigned)(wm * 128 + mf * 32 + l32) * 64 +
                     ((((unsigned)ks * 2 + half) ^ (unsigned)(lane & 7)) * 8);
#pragma unroll
  for (int nf = 0; nf < 2; ++nf)
#pragma unroll
    for (int ks = 0; ks < 4; ++ks)
      bofs[nf][ks] = breg + (unsigned)(wn * 64 + nf * 32 + l32) * 64 +
                     ((((unsigned)ks * 2 + half) ^ (unsigned)(lane & 7)) * 8);

  f32x16 acc[4][2];
#pragma unroll
  for (int i = 0; i < 4; ++i)
#pragma unroll
    for (int j = 0; j < 2; ++j) acc[i][j] = (f32x16)0.f;

  // prologue: stage tile 0 -> buffer 0
#pragma unroll
  for (int c = 0; c < 4; ++c) gll16(srcA[c], &lds[dstA[c]]);
#pragma unroll
  for (int c = 0; c < 2; ++c) {
    gll16(srcG[c], &lds[16384u + dstB[c]]);
    gll16(srcU[c], &lds[24576u + dstB[c]]);
  }
  WAITV0();
  BAR();

  for (int t = 0; t < 16; ++t) {
    unsigned bo  = (unsigned)(t & 1) * 32768u;
    unsigned bo1 = bo ^ 32768u;
    if (t < 15) {                                   // stage t+1 early: full-tile latency cover
      int kel = (t + 1) * 64;
#pragma unroll
      for (int c = 0; c < 4; ++c) gll16(srcA[c] + kel, &lds[bo1 + dstA[c]]);
#pragma unroll
      for (int c = 0; c < 2; ++c) {
        gll16(srcG[c] + kel, &lds[bo1 + 16384u + dstB[c]]);
        gll16(srcU[c] + kel, &lds[bo1 + 24576u + dstB[c]]);
      }
    }
    PRIO1();
#pragma unroll
    for (int ks = 0; ks < 4; ++ks) {
      bf16x8 b0 = *(const bf16x8*)&lds[bo + bofs[0][ks]];
      bf16x8 b1 = *(const bf16x8*)&lds[bo + bofs[1][ks]];
#pragma unroll
      for (int mf = 0; mf < 4; ++mf) {
        bf16x8 a = *(const bf16x8*)&lds[bo + aofs[mf][ks]];
        acc[mf][0] = mfma3216(a, b0, acc[mf][0]);
        acc[mf][1] = mfma3216(a, b1, acc[mf][1]);
      }
    }
    PRIO0();
    WAITV0();        // 8 loads issued a full tile ago -> near-complete
    BAR();
  }

  // epilogue: U-waves dump f32 acc to LDS; G-waves fuse SiLU(g)*u -> hbuf
  if (grp == 1) {
#pragma unroll
    for (int mf = 0; mf < 4; ++mf)
#pragma unroll
      for (int rr = 0; rr < 16; ++rr) {
        int row = wm * 128 + mf * 32 + (rr & 3) + 8 * (rr >> 2) + 4 * half;
#pragma unroll
        for (int nf = 0; nf < 2; ++nf)
          uex[row * 128 + wn * 64 + nf * 32 + l32] = acc[mf][nf][rr];
      }
  }
  BAR();
  if (grp == 0) {
#pragma unroll
    for (int mf = 0; mf < 4; ++mf)
#pragma unroll
      for (int rr = 0; rr < 16; ++rr) {
        int row = wm * 128 + mf * 32 + (rr & 3) + 8 * (rr >> 2) + 4 * half;
        size_t base = (size_t)(mt * 256 + row) * I_DIM + nt * 128;
#pragma unroll
        for (int nf = 0; nf < 2; ++nf) {
          float g = acc[mf][nf][rr];
          float u = uex[row * 128 + wn * 64 + nf * 32 + l32];
          float sg = g / (1.f + __expf(-g));
          hbuf[base + wn * 64 + nf * 32 + l32] = f2bf(sg * u);
        }
      }
  }
}

// ---------------- K7: GEMM2 256x128, 32x32x16 MFMA, BK=64, 3-buffer counted-vmcnt ----------------
// grid: x = nt (8), y = mt (72); 512 threads = 8 waves (2M x 4N), wave tile 128x32; 144KB LDS
__global__ __launch_bounds__(512, 2) void k_gemm2(
    const unsigned short* __restrict__ hbuf, const unsigned short* __restrict__ wdT,
    const int* __restrict__ tile_e, unsigned short* __restrict__ obuf)
{
  int mt = blockIdx.y, nt = blockIdx.x;
  int e = tile_e[mt];
  if (e < 0) return;
  // buffer: A[256][64] @0, B[128][64] @16384 (elems), 24576 elems/buffer, x3
  __shared__ unsigned short lds[73728];
  int tid = threadIdx.x;
  int wave = tid >> 6, lane = tid & 63;
  int wm = wave >> 2, wn = wave & 3;      // 2M x 4N
  int l32 = lane & 31, half = lane >> 5;

  int rp = lane >> 3;
  int chunk = (lane & 7) ^ rp;
  const unsigned short* sA[2][2]; const unsigned short* sB[2];
  unsigned dA[2][2], dB[2];
#pragma unroll
  for (int h = 0; h < 2; ++h)
#pragma unroll
    for (int c = 0; c < 2; ++c) {
      int rowp = wave * 16 + c * 8 + rp;
      sA[h][c] = hbuf + (size_t)(mt * 256 + h * 128 + rowp) * I_DIM + chunk * 8;
      dA[h][c] = (unsigned)(h * 128 + wave * 16 + c * 8) * 64;
    }
#pragma unroll
  for (int c = 0; c < 2; ++c) {
    int rowp = wave * 16 + c * 8 + rp;
    sB[c] = wdT + ((size_t)e * H_DIM + nt * 128 + rowp) * I_DIM + chunk * 8;
    dB[c] = (unsigned)(wave * 16 + c * 8) * 64;
  }

  // precomputed swizzled read offsets
  unsigned aofs[4][4], bofs[4];
#pragma unroll
  for (int mf = 0; mf < 4; ++mf)
#pragma unroll
    for (int ks = 0; ks < 4; ++ks)
      aofs[mf][ks] = (unsigned)(wm * 128 + mf * 32 + l32) * 64 +
                     ((((unsigned)ks * 2 + half) ^ (unsigned)(lane & 7)) * 8);
#pragma unroll
  for (int ks = 0; ks < 4; ++ks)
    bofs[ks] = 16384u + (unsigned)(wn * 32 + l32) * 64 +
               ((((unsigned)ks * 2 + half) ^ (unsigned)(lane & 7)) * 8);

  f32x16 acc[4];
#pragma unroll
  for (int i = 0; i < 4; ++i) acc[i] = (f32x16)0.f;

  // prologue: stage tiles 0,1 into buffers 0,1 (6 ops each); wait oldest 6
#pragma unroll
  for (int tt = 0; tt < 2; ++tt) {
    unsigned bo = (unsigned)tt * 24576;
    int kel = tt * 64;
#pragma unroll
    for (int h = 0; h < 2; ++h)
#pragma unroll
      for (int c = 0; c < 2; ++c) gll16(sA[h][c] + kel, &lds[bo + dA[h][c]]);
#pragma unroll
    for (int c = 0; c < 2; ++c) gll16(sB[c] + kel, &lds[bo + 16384 + dB[c]]);
  }
  WAITV6();
  BAR();

  unsigned boA = 0, boB = 24576, boC = 49152;   // read, next, stage-target(t+2)
  for (int t = 0; t < 32; ++t) {
    int kel = (t + 2) * 64;
    bool pf = (t < 30);
    bf16x8 b[4];
#pragma unroll
    for (int ks = 0; ks < 4; ++ks) b[ks] = *(const bf16x8*)&lds[boA + bofs[ks]];
    // ---- P0: ks 0-1 ----
    {
      bf16x8 a[4][2];
#pragma unroll
      for (int mf = 0; mf < 4; ++mf)
#pragma unroll
        for (int ks = 0; ks < 2; ++ks)
          a[mf][ks] = *(const bf16x8*)&lds[boA + aofs[mf][ks]];
      if (pf) {
#pragma unroll
        for (int h = 0; h < 2; ++h)
#pragma unroll
          for (int c = 0; c < 2; ++c) gll16(sA[h][c] + kel, &lds[boC + dA[h][c]]);
      }
      BAR();
      PRIO1();
#pragma unroll
      for (int mf = 0; mf < 4; ++mf)
#pragma unroll
        for (int ks = 0; ks < 2; ++ks) acc[mf] = mfma3216(a[mf][ks], b[ks], acc[mf]);
      PRIO0();
      BAR();
    }
    // ---- P1: ks 2-3; boundary counted wait ----
    {
      bf16x8 a[4][2];
#pragma unroll
      for (int mf = 0; mf < 4; ++mf)
#pragma unroll
        for (int ks = 0; ks < 2; ++ks)
          a[mf][ks] = *(const bf16x8*)&lds[boA + aofs[mf][2 + ks]];
      if (pf) {
#pragma unroll
        for (int c = 0; c < 2; ++c) gll16(sB[c] + kel, &lds[boC + 16384 + dB[c]]);
      }
      BAR();
      PRIO1();
#pragma unroll
      for (int mf = 0; mf < 4; ++mf)
#pragma unroll
        for (int ks = 0; ks < 2; ++ks) acc[mf] = mfma3216(a[mf][ks], b[2 + ks], acc[mf]);
      PRIO0();
    }
    if (pf) { WAITV6(); } else { WAITV0(); }   // never drain to 0 in steady state
    BAR();
    unsigned tmp = boA; boA = boB; boB = boC; boC = tmp;
  }
  // epilogue: bf16 store to obuf
#pragma unroll
  for (int mf = 0; mf < 4; ++mf)
#pragma unroll
    for (int rr = 0; rr < 16; ++rr) {
      int s = mt * 256 + wm * 128 + mf * 32 + (rr & 3) + 8 * (rr >> 2) + 4 * half;
      obuf[(size_t)s * H_DIM + nt * 128 + wn * 32 + l32] = f2bf(acc[mf][rr]);
    }
}

// ---------------- K8: gather-combine y[t] = w0*obuf[s0] + w1*obuf[s1] ----------------
__global__ __launch_bounds__(256) void k_final(
    const unsigned short* __restrict__ obuf, const int* __restrict__ tslot,
    const float* __restrict__ bw, float* __restrict__ y)
{
  int t = blockIdx.x;
  int s0 = tslot[t * 2], s1 = tslot[t * 2 + 1];
  float w0 = bw[s0], w1 = bw[s1];
  int c = threadIdx.x * 4;
  u16x4 o0 = *(const u16x4*)&obuf[(size_t)s0 * H_DIM + c];
  u16x4 o1 = *(const u16x4*)&obuf[(size_t)s1 * H_DIM + c];
  float4 r;
  r.x = w0 * bf2f(o0[0]) + w1 * bf2f(o1[0]);
  r.y = w0 * bf2f(o0[1]) + w1 * bf2f(o1[1]);
  r.z = w0 * bf2f(o0[2]) + w1 * bf2f(o1[2]);
  r.w = w0 * bf2f(o0[3]) + w1 * bf2f(o1[3]);
  *(float4*)&y[(size_t)t * H_DIM + c] = r;
}

extern "C" void kernel_launch(void* const* d_in, const int* in_sizes, int n_in,
                              void* d_out, int out_size, void* d_ws, size_t ws_size,
                              hipStream_t stream)
{
  (void)in_sizes; (void)n_in; (void)out_size; (void)ws_size;
  const float* x  = (const float*)d_in[0];
  const float* gw = (const float*)d_in[1];
  const float* wg = (const float*)d_in[2];
  const float* wu = (const float*)d_in[3];
  const float* wd = (const float*)d_in[4];
  char* ws = (char*)d_ws;

  int*   topk_i = (int*)  (ws + OFF_TOPK_I);
  float* topk_w = (float*)(ws + OFF_TOPK_W);
  int*   counts = (int*)  (ws + OFF_COUNTS);
  float* loadw  = (float*)(ws + OFF_LOAD);
  int*   cursor = (int*)  (ws + OFF_CURSOR);
  int*   po     = (int*)  (ws + OFF_PO);
  int*   tile_e = (int*)  (ws + OFF_TILE_E);
  int*   btok   = (int*)  (ws + OFF_BTOK);
  float* bw     = (float*)(ws + OFF_BW);
  int*   tslot  = (int*)  (ws + OFF_TSLOT);
  unsigned short* wgT  = (unsigned short*)(ws + OFF_WGT);
  unsigned short* wuT  = (unsigned short*)(ws + OFF_WUT);
  unsigned short* wdT  = (unsigned short*)(ws + OFF_WDT);
  unsigned short* hbuf = (unsigned short*)(ws + OFF_HB);
  unsigned short* xb   = (unsigned short*)(ws + OFF_XB);
  unsigned short* obuf = (unsigned short*)(ws + OFF_WGT);  // reuse wgT+wuT (dead after gemm1)
  float* yout = (float*)d_out;

  (void)hipMemsetAsync(ws, 0, CTRL_BYTES, stream);
  k_prep<<<14336, 256, 0, stream>>>(x, gw, wg, wu, wd, xb, wgT, wuT, wdT, topk_i, topk_w);
  k_hist<<<16, 256, 0, stream>>>(topk_i, topk_w, counts, loadw);
  k_offsets<<<1, 256, 0, stream>>>(counts, loadw, po, tile_e, (float*)d_out);
  k_bucket<<<16, 256, 0, stream>>>(topk_i, topk_w, po, cursor, btok, bw, tslot);
  k_gemm1<<<dim3(I_DIM / 128, MT_MAX), 512, 0, stream>>>(xb, wgT, wuT, btok, tile_e, hbuf);
  k_gemm2<<<dim3(H_DIM / 128, MT_MAX), 512, 0, stream>>>(hbuf, wdT, tile_e, obuf);
  k_final<<<N_TOK, 256, 0, stream>>>(obuf, tslot, bw, yout);
}